// Round 2
// baseline (614.501 us; speedup 1.0000x reference)
//
#include <hip/hip_runtime.h>
#include <hip/hip_bf16.h>

typedef __attribute__((ext_vector_type(8))) short short8;
typedef __attribute__((ext_vector_type(4))) float f32x4;

#define B_N 1024
#define D_K 512
#define C_N 100000
#define SCALE_F 64.0f
#define MARGIN_F 0.35f
#define BN 64
#define NT_ 1563   // ceil(100000/64)

__device__ __forceinline__ float dot4(float4 a, float4 b) {
    return a.x * b.x + a.y * b.y + a.z * b.z + a.w * b.w;
}

// round-to-nearest-even f32 -> bf16 bits
__device__ __forceinline__ ushort f2b(float f) {
    unsigned int u = __float_as_uint(f);
    u = (u + 0x7FFFu + ((u >> 16) & 1u)) >> 16;
    return (ushort)u;
}

// ---------------- kernel A: normalize x rows -> bf16 ----------------
__global__ void norm_x_kernel(const float* __restrict__ x,
                              ushort* __restrict__ xnb) {
    int row = blockIdx.x * 4 + (threadIdx.x >> 6);
    int l = threadIdx.x & 63;
    const float4* rp = (const float4*)(x + (size_t)row * D_K);
    float4 a = rp[l], b = rp[64 + l];
    float ssq = dot4(a, a) + dot4(b, b);
#pragma unroll
    for (int m = 1; m < 64; m <<= 1) ssq += __shfl_xor(ssq, m);
    float inv = 1.0f / fmaxf(sqrtf(ssq), 1e-12f);
    a.x *= inv; a.y *= inv; a.z *= inv; a.w *= inv;
    b.x *= inv; b.y *= inv; b.z *= inv; b.w *= inv;
    ushort4 ua; ua.x = f2b(a.x); ua.y = f2b(a.y); ua.z = f2b(a.z); ua.w = f2b(a.w);
    ushort4 ub; ub.x = f2b(b.x); ub.y = f2b(b.y); ub.z = f2b(b.z); ub.w = f2b(b.w);
    ushort4* obp = (ushort4*)(xnb + (size_t)row * D_K);
    obp[l] = ua; obp[64 + l] = ub;
}

// ------------- kernel B: disc loss partial + exact target logit -------------
__global__ void disc_kernel(const float* __restrict__ x,
                            const int* __restrict__ target,
                            const float* __restrict__ ida,
                            const float* __restrict__ bmat,
                            float* __restrict__ sums,
                            float* __restrict__ tlogit) {
    int row = blockIdx.x * 4 + (threadIdx.x >> 6);
    int l = threadIdx.x & 63;
    long t = (long)target[row];
    const float4* xp = (const float4*)(x + (size_t)row * D_K);
    const float4* wp = (const float4*)(ida + (size_t)t * D_K);
    const float4* bp = (const float4*)(bmat + (size_t)t * D_K);
    float4 x0 = xp[l], x1 = xp[64 + l];
    float4 w0 = wp[l], w1 = wp[64 + l];
    float4 b0 = bp[l], b1 = bp[64 + l];
    float xssq = dot4(x0, x0) + dot4(x1, x1);
    float wssq = dot4(w0, w0) + dot4(w1, w1);
    float bssq = dot4(b0, b0) + dot4(b1, b1);
#pragma unroll
    for (int m = 1; m < 64; m <<= 1) {
        xssq += __shfl_xor(xssq, m);
        wssq += __shfl_xor(wssq, m);
        bssq += __shfl_xor(bssq, m);
    }
    float xinv = 1.0f / fmaxf(sqrtf(xssq), 1e-12f);
    float winv = 1.0f / fmaxf(sqrtf(wssq), 1e-12f);
    float btn = sqrtf(bssq);
    float cs = fminf(btn, 0.05f) / fmaxf(btn, 1e-12f);

    float xs[8] = {x0.x, x0.y, x0.z, x0.w, x1.x, x1.y, x1.z, x1.w};
    float wv[8] = {w0.x, w0.y, w0.z, w0.w, w1.x, w1.y, w1.z, w1.w};
    float bv[8] = {b0.x, b0.y, b0.z, b0.w, b1.x, b1.y, b1.z, b1.w};
    float rss = 0.0f, dt = 0.0f;
#pragma unroll
    for (int i = 0; i < 8; ++i) {
        float xn = xs[i] * xinv;
        float wn = wv[i] * winv;
        float d = xn - wn;
        float r = d - bv[i] * cs;
        rss += r * r;
        dt += xn * wn;
    }
#pragma unroll
    for (int m = 1; m < 64; m <<= 1) {
        rss += __shfl_xor(rss, m);
        dt += __shfl_xor(dt, m);
    }
    if (l == 0) {
        atomicAdd(&sums[0], sqrtf(rss));
        tlogit[row] = SCALE_F * dt;
    }
}

// ------------- kernel C: persistent-W GEMM with fused norm + tile-LSE -------------
// One block per 64-class tile. W staged (raw f32 -> raw bf16) into LDS once;
// per-column inv-norm applied in epilogue. Barrier-free MFMA k-loop.
__global__ __launch_bounds__(512, 4) void gemm_lse_kernel(const ushort* __restrict__ A,
                                                          const float* __restrict__ Wf,
                                                          float* __restrict__ pm,
                                                          float* __restrict__ pse) {
    // W LDS layout: [kblk 0..63][row 0..63][8 bf16] -> ushort idx kblk*512 + row*8
    __shared__ ushort Wl[64 * 512];
    __shared__ float Winv[64];
    __shared__ float epim[2][256];
    __shared__ float epis[2][256];

    int tid = threadIdx.x;
    int l = tid & 63, wave = tid >> 6;
    int wm = wave >> 1, wn = wave & 1;      // 4 M-wave-rows x 2 N-wave-cols
    int bx = blockIdx.x;
    int n0 = bx * BN;

    // ---- stage: read raw f32 W rows (coalesced), ssq + bf16 convert ----
    {
        int rloc = wave * 8 + (l >> 3);     // 0..63
        int rg = n0 + rloc;
        if (rg > C_N - 1) rg = C_N - 1;
        const float* src = Wf + (size_t)rg * D_K;
        float ssq = 0.0f;
#pragma unroll
        for (int p = 0; p < 8; ++p) {
            int kb = (l & 7) + p * 8;       // kblk 0..63
            float4 v0 = *(const float4*)(src + kb * 8);
            float4 v1 = *(const float4*)(src + kb * 8 + 4);
            ssq += dot4(v0, v0) + dot4(v1, v1);
            short8 h;
            h[0] = (short)f2b(v0.x); h[1] = (short)f2b(v0.y);
            h[2] = (short)f2b(v0.z); h[3] = (short)f2b(v0.w);
            h[4] = (short)f2b(v1.x); h[5] = (short)f2b(v1.y);
            h[6] = (short)f2b(v1.z); h[7] = (short)f2b(v1.w);
            *(short8*)&Wl[kb * 512 + rloc * 8] = h;
        }
        ssq += __shfl_xor(ssq, 1);
        ssq += __shfl_xor(ssq, 2);
        ssq += __shfl_xor(ssq, 4);
        if ((l & 7) == 0) Winv[rloc] = 1.0f / fmaxf(sqrtf(ssq), 1e-12f);
    }
    __syncthreads();

    int cl = l & 15, hi = l >> 4;
    float scl[2];
    scl[0] = SCALE_F * Winv[wn * 32 + cl];
    scl[1] = SCALE_F * Winv[wn * 32 + 16 + cl];
    int wbase = hi * 512 + (wn * 32 + cl) * 8;   // ushort index base for W frags

    f32x4 zero4 = {0.0f, 0.0f, 0.0f, 0.0f};

    for (int mt = 0; mt < 4; ++mt) {
        const ushort* pA = A + (size_t)(mt * 256 + wm * 64 + cl) * D_K + hi * 8;
        f32x4 acc[4][2];
#pragma unroll
        for (int mi = 0; mi < 4; ++mi) {
            acc[mi][0] = zero4;
            acc[mi][1] = zero4;
        }
        // barrier-free k-loop: W from persistent LDS, A from L1/L2-resident global
#pragma unroll 2
        for (int ks = 0; ks < 16; ++ks) {
            short8 af[4], wf[2];
#pragma unroll
            for (int mi = 0; mi < 4; ++mi)
                af[mi] = *(const short8*)(pA + mi * (16 * D_K) + ks * 32);
#pragma unroll
            for (int ni = 0; ni < 2; ++ni)
                wf[ni] = *(const short8*)&Wl[wbase + ks * 2048 + ni * 128];
#pragma unroll
            for (int mi = 0; mi < 4; ++mi)
#pragma unroll
                for (int ni = 0; ni < 2; ++ni)
                    acc[mi][ni] = __builtin_amdgcn_mfma_f32_16x16x32_bf16(af[mi], wf[ni], acc[mi][ni], 0, 0, 0);
        }
        // ---- epilogue: per-row max/sumexp over this block's 64 columns ----
        bool v1ok = (n0 + wn * 32 + 16 + cl) < C_N;   // first 32 cols always valid
#pragma unroll
        for (int mi = 0; mi < 4; ++mi) {
#pragma unroll
            for (int j = 0; j < 4; ++j) {
                float s0 = acc[mi][0][j] * scl[0];
                float s1 = v1ok ? acc[mi][1][j] * scl[1] : -INFINITY;
                float mx = fmaxf(s0, s1);
#pragma unroll
                for (int xm = 1; xm < 16; xm <<= 1) mx = fmaxf(mx, __shfl_xor(mx, xm));
                float se = __expf(s0 - mx) + (v1ok ? __expf(s1 - mx) : 0.0f);
#pragma unroll
                for (int xm = 1; xm < 16; xm <<= 1) se += __shfl_xor(se, xm);
                if (cl == 0) {
                    int r = wm * 64 + mi * 16 + hi * 4 + j;
                    epim[wn][r] = mx;
                    epis[wn][r] = se;
                }
            }
        }
        __syncthreads();
        if (tid < 256) {
            float m0 = epim[0][tid], m1 = epim[1][tid];
            float mm = fmaxf(m0, m1);
            float se = epis[0][tid] * __expf(m0 - mm) + epis[1][tid] * __expf(m1 - mm);
            size_t o = (size_t)bx * B_N + mt * 256 + tid;   // [nt][row] coalesced
            pm[o] = mm;
            pse[o] = se;
        }
        __syncthreads();
    }
}

// ------------- kernel D: combine per-row partials -> nll, accumulate -------------
// 16 blocks x 256 threads; block handles 64 rows; coalesced [nt][row] reads.
__global__ void row_lse_kernel(const float* __restrict__ pm,
                               const float* __restrict__ pse,
                               const float* __restrict__ tlogit,
                               float* __restrict__ sums) {
    __shared__ float sm[4][64];
    __shared__ float ss[4][64];
    int r0 = blockIdx.x * 64;
    int tid = threadIdx.x, l = tid & 63, w = tid >> 6;
    int row = r0 + l;

    float m = -INFINITY, se = 0.0f;
    for (int nt = w; nt < NT_; nt += 4) {
        float pmv = pm[(size_t)nt * B_N + row];
        float psev = pse[(size_t)nt * B_N + row];
        float nm = fmaxf(m, pmv);
        se = se * __expf(m - nm) + psev * __expf(pmv - nm);
        m = nm;
    }
    sm[w][l] = m; ss[w][l] = se;
    __syncthreads();
    if (tid < 64) {
        float M = fmaxf(fmaxf(sm[0][l], sm[1][l]), fmaxf(sm[2][l], sm[3][l]));
        float S = ss[0][l] * __expf(sm[0][l] - M) + ss[1][l] * __expf(sm[1][l] - M) +
                  ss[2][l] * __expf(sm[2][l] - M) + ss[3][l] * __expf(sm[3][l] - M);
        float lse = M + logf(S);
        float st = tlogit[r0 + l];
        float corr = __expf(st - lse) * (__expf(-SCALE_F * MARGIN_F) - 1.0f);
        float lse2 = lse + log1pf(corr);
        float nll = lse2 - (st - SCALE_F * MARGIN_F);
#pragma unroll
        for (int xm = 1; xm < 64; xm <<= 1) nll += __shfl_xor(nll, xm);
        if (l == 0) atomicAdd(&sums[1], nll);
    }
}

// ------------- kernel E: finalize scalar output -------------
__global__ void finalize_kernel(const float* __restrict__ sums, float* __restrict__ out) {
    float disc = sums[0] * (1.0f / B_N);
    float logp = sums[1] * (1.0f / B_N);
    float p = __expf(-logp);
    float om = 1.0f - p;
    out[0] = 0.4f * disc + om * om * logp;
}

extern "C" void kernel_launch(void* const* d_in, const int* in_sizes, int n_in,
                              void* d_out, int out_size, void* d_ws, size_t ws_size,
                              hipStream_t stream) {
    const float* x = (const float*)d_in[0];
    const int* target = (const int*)d_in[1];
    const float* ida = (const float*)d_in[2];
    const float* bmat = (const float*)d_in[3];
    float* out = (float*)d_out;

    char* ws = (char*)d_ws;
    size_t off = 0;
    ushort* xnb = (ushort*)(ws + off);   off += (size_t)B_N * D_K * 2;     // 1 MB
    float* pm = (float*)(ws + off);      off += (size_t)NT_ * B_N * 4;     // 6.4 MB
    float* pse = (float*)(ws + off);     off += (size_t)NT_ * B_N * 4;     // 6.4 MB
    float* tlogit = (float*)(ws + off);  off += (size_t)B_N * 4;
    float* sums = (float*)(ws + off);    off += 256;

    hipMemsetAsync(sums, 0, 2 * sizeof(float), stream);

    norm_x_kernel<<<B_N / 4, 256, 0, stream>>>(x, xnb);
    disc_kernel<<<B_N / 4, 256, 0, stream>>>(x, target, ida, bmat, sums, tlogit);
    gemm_lse_kernel<<<NT_, 512, 0, stream>>>(xnb, ida, pm, pse);
    row_lse_kernel<<<B_N / 64, 256, 0, stream>>>(pm, pse, tlogit, sums);
    finalize_kernel<<<1, 1, 0, stream>>>(sums, out);
}

// Round 3
// 308.040 us; speedup vs baseline: 1.9949x; 1.9949x over previous
//
#include <hip/hip_runtime.h>
#include <hip/hip_bf16.h>

typedef __attribute__((ext_vector_type(8))) short short8;
typedef __attribute__((ext_vector_type(4))) float f32x4;

#define B_N 1024
#define D_K 512
#define C_N 100000
#define SCALE_F 64.0f
#define MARGIN_F 0.35f
#define BM 128
#define BN 128
#define BK 64
#define NT_ 782   // ceil(100000/128)
#define MT_ 8     // 1024/128

__device__ __forceinline__ float dot4(float4 a, float4 b) {
    return a.x * b.x + a.y * b.y + a.z * b.z + a.w * b.w;
}

// round-to-nearest-even f32 -> bf16 bits
__device__ __forceinline__ ushort f2b(float f) {
    unsigned int u = __float_as_uint(f);
    u = (u + 0x7FFFu + ((u >> 16) & 1u)) >> 16;
    return (ushort)u;
}

// ---------------- kernel A: normalize x rows -> bf16 ----------------
__global__ void norm_x_kernel(const float* __restrict__ x,
                              ushort* __restrict__ xnb) {
    int row = blockIdx.x * 4 + (threadIdx.x >> 6);
    int l = threadIdx.x & 63;
    const float4* rp = (const float4*)(x + (size_t)row * D_K);
    float4 a = rp[l], b = rp[64 + l];
    float ssq = dot4(a, a) + dot4(b, b);
#pragma unroll
    for (int m = 1; m < 64; m <<= 1) ssq += __shfl_xor(ssq, m);
    float inv = 1.0f / fmaxf(sqrtf(ssq), 1e-12f);
    a.x *= inv; a.y *= inv; a.z *= inv; a.w *= inv;
    b.x *= inv; b.y *= inv; b.z *= inv; b.w *= inv;
    ushort4 ua; ua.x = f2b(a.x); ua.y = f2b(a.y); ua.z = f2b(a.z); ua.w = f2b(a.w);
    ushort4 ub; ub.x = f2b(b.x); ub.y = f2b(b.y); ub.z = f2b(b.z); ub.w = f2b(b.w);
    ushort4* obp = (ushort4*)(xnb + (size_t)row * D_K);
    obp[l] = ua; obp[64 + l] = ub;
}

// ---------------- kernel B: normalize id_agent rows -> bf16 ----------------
__global__ void norm_w_kernel(const float* __restrict__ w,
                              ushort* __restrict__ wb) {
    int row = blockIdx.x * 4 + (threadIdx.x >> 6);
    int l = threadIdx.x & 63;
    const float4* rp = (const float4*)(w + (size_t)row * D_K);
    float4 a = rp[l], b = rp[64 + l];
    float ssq = dot4(a, a) + dot4(b, b);
#pragma unroll
    for (int m = 1; m < 64; m <<= 1) ssq += __shfl_xor(ssq, m);
    float inv = 1.0f / fmaxf(sqrtf(ssq), 1e-12f);
    a.x *= inv; a.y *= inv; a.z *= inv; a.w *= inv;
    b.x *= inv; b.y *= inv; b.z *= inv; b.w *= inv;
    ushort4 ua; ua.x = f2b(a.x); ua.y = f2b(a.y); ua.z = f2b(a.z); ua.w = f2b(a.w);
    ushort4 ub; ub.x = f2b(b.x); ub.y = f2b(b.y); ub.z = f2b(b.z); ub.w = f2b(b.w);
    ushort4* obp = (ushort4*)(wb + (size_t)row * D_K);
    obp[l] = ua; obp[64 + l] = ub;
}

// ------------- kernel C: disc loss partial + exact target logit -------------
__global__ void disc_kernel(const float* __restrict__ x,
                            const int* __restrict__ target,
                            const float* __restrict__ ida,
                            const float* __restrict__ bmat,
                            float* __restrict__ sums,
                            float* __restrict__ tlogit) {
    int row = blockIdx.x * 4 + (threadIdx.x >> 6);
    int l = threadIdx.x & 63;
    long t = (long)target[row];
    const float4* xp = (const float4*)(x + (size_t)row * D_K);
    const float4* wp = (const float4*)(ida + (size_t)t * D_K);
    const float4* bp = (const float4*)(bmat + (size_t)t * D_K);
    float4 x0 = xp[l], x1 = xp[64 + l];
    float4 w0 = wp[l], w1 = wp[64 + l];
    float4 b0 = bp[l], b1 = bp[64 + l];
    float xssq = dot4(x0, x0) + dot4(x1, x1);
    float wssq = dot4(w0, w0) + dot4(w1, w1);
    float bssq = dot4(b0, b0) + dot4(b1, b1);
#pragma unroll
    for (int m = 1; m < 64; m <<= 1) {
        xssq += __shfl_xor(xssq, m);
        wssq += __shfl_xor(wssq, m);
        bssq += __shfl_xor(bssq, m);
    }
    float xinv = 1.0f / fmaxf(sqrtf(xssq), 1e-12f);
    float winv = 1.0f / fmaxf(sqrtf(wssq), 1e-12f);
    float btn = sqrtf(bssq);
    float cs = fminf(btn, 0.05f) / fmaxf(btn, 1e-12f);

    float xs[8] = {x0.x, x0.y, x0.z, x0.w, x1.x, x1.y, x1.z, x1.w};
    float wv[8] = {w0.x, w0.y, w0.z, w0.w, w1.x, w1.y, w1.z, w1.w};
    float bv[8] = {b0.x, b0.y, b0.z, b0.w, b1.x, b1.y, b1.z, b1.w};
    float rss = 0.0f, dt = 0.0f;
#pragma unroll
    for (int i = 0; i < 8; ++i) {
        float xn = xs[i] * xinv;
        float wn = wv[i] * winv;
        float d = xn - wn;
        float r = d - bv[i] * cs;
        rss += r * r;
        dt += xn * wn;
    }
#pragma unroll
    for (int m = 1; m < 64; m <<= 1) {
        rss += __shfl_xor(rss, m);
        dt += __shfl_xor(dt, m);
    }
    if (l == 0) {
        atomicAdd(&sums[0], sqrtf(rss));
        tlogit[row] = SCALE_F * dt;
    }
}

// ------------- kernel D: bf16 MFMA GEMM, XCD-swizzled, BK=64, fused tile-LSE -------------
__global__ __launch_bounds__(256, 4) void gemm_lse_kernel(const ushort* __restrict__ A,
                                                          const ushort* __restrict__ W,
                                                          float* __restrict__ pm,
                                                          float* __restrict__ pse) {
    __shared__ ushort As[BM * BK];   // 16 KB, linear [row][64]
    __shared__ ushort Bs[BN * BK];   // 16 KB
    __shared__ float smx[2][BM];
    __shared__ float sse[2][BM];

    int tid = threadIdx.x;
    int wave = tid >> 6, l = tid & 63;
    int wm = wave >> 1, wn = wave & 1;

    // XCD-bijective swizzle: 6256 blocks, 8 XCDs round-robin (xcd = bid % 8).
    // Give each XCD a contiguous chunk of tile-space ordered (nt major, mt minor)
    // so all 8 blocks sharing a W-tile land on one XCD's L2.
    int tile = (blockIdx.x & 7) * NT_ + (blockIdx.x >> 3);
    int nt = tile >> 3, mt = tile & 7;
    int m0 = mt * BM, n0 = nt * BN;

    int srow = l >> 3;        // row offset 0..7 within an 8-row staging chunk
    int scol = (l & 7) * 8;   // k-element offset of this lane's 16B

    f32x4 zero4 = {0.0f, 0.0f, 0.0f, 0.0f};
    f32x4 acc[4][4];
#pragma unroll
    for (int i = 0; i < 4; ++i)
#pragma unroll
        for (int j = 0; j < 4; ++j) acc[i][j] = zero4;

    int cl = l & 15, hi = l >> 4;

    for (int kt = 0; kt < D_K; kt += BK) {
#pragma unroll
        for (int i = 0; i < 4; ++i) {
            int rb = wave * 32 + i * 8;
            const ushort* ga = A + (size_t)(m0 + rb + srow) * D_K + kt + scol;
            __builtin_amdgcn_global_load_lds(
                (const __attribute__((address_space(1))) void*)ga,
                (__attribute__((address_space(3))) void*)&As[rb * BK], 16, 0, 0);
            int rn = n0 + rb + srow;
            rn = rn < C_N ? rn : C_N - 1;
            const ushort* gb = W + (size_t)rn * D_K + kt + scol;
            __builtin_amdgcn_global_load_lds(
                (const __attribute__((address_space(1))) void*)gb,
                (__attribute__((address_space(3))) void*)&Bs[rb * BK], 16, 0, 0);
        }
        __syncthreads();

#pragma unroll
        for (int kk = 0; kk < 2; ++kk) {
            short8 af[4], bfr[4];
#pragma unroll
            for (int mi = 0; mi < 4; ++mi)
                af[mi] = *(const short8*)&As[(wm * 64 + mi * 16 + cl) * BK + kk * 32 + hi * 8];
#pragma unroll
            for (int ni = 0; ni < 4; ++ni)
                bfr[ni] = *(const short8*)&Bs[(wn * 64 + ni * 16 + cl) * BK + kk * 32 + hi * 8];
#pragma unroll
            for (int mi = 0; mi < 4; ++mi)
#pragma unroll
                for (int ni = 0; ni < 4; ++ni)
                    acc[mi][ni] = __builtin_amdgcn_mfma_f32_16x16x32_bf16(af[mi], bfr[ni], acc[mi][ni], 0, 0, 0);
        }
        __syncthreads();
    }

    // epilogue: per-row (within this tile) max and sum(exp)
#pragma unroll
    for (int mi = 0; mi < 4; ++mi) {
#pragma unroll
        for (int j = 0; j < 4; ++j) {
            float s[4];
#pragma unroll
            for (int ni = 0; ni < 4; ++ni) {
                int cg = n0 + wn * 64 + ni * 16 + cl;
                s[ni] = (cg < C_N) ? acc[mi][ni][j] * SCALE_F : -INFINITY;
            }
            float mx = fmaxf(fmaxf(s[0], s[1]), fmaxf(s[2], s[3]));
#pragma unroll
            for (int xm = 1; xm < 16; xm <<= 1) mx = fmaxf(mx, __shfl_xor(mx, xm));
            float se = 0.0f;
#pragma unroll
            for (int ni = 0; ni < 4; ++ni)
                se += (s[ni] > -INFINITY) ? __expf(s[ni] - mx) : 0.0f;
#pragma unroll
            for (int xm = 1; xm < 16; xm <<= 1) se += __shfl_xor(se, xm);
            if (cl == 0) {
                int r = wm * 64 + mi * 16 + hi * 4 + j;
                smx[wn][r] = mx;
                sse[wn][r] = se;
            }
        }
    }
    __syncthreads();
    if (tid < BM) {
        float ma = smx[0][tid], mb = smx[1][tid];
        float mm = fmaxf(ma, mb);
        float se = 0.0f;
        if (ma > -INFINITY) se += sse[0][tid] * __expf(ma - mm);
        if (mb > -INFINITY) se += sse[1][tid] * __expf(mb - mm);
        size_t idx = (size_t)nt * B_N + m0 + tid;   // [nt][row] coalesced
        pm[idx] = mm;
        pse[idx] = se;
    }
}

// ------------- kernel E: combine per-row partials -> nll, accumulate -------------
// 16 blocks x 256 threads; block handles 64 rows; coalesced [nt][row] reads.
__global__ void row_lse_kernel(const float* __restrict__ pm,
                               const float* __restrict__ pse,
                               const float* __restrict__ tlogit,
                               float* __restrict__ sums) {
    __shared__ float sm[4][64];
    __shared__ float ss[4][64];
    int r0 = blockIdx.x * 64;
    int tid = threadIdx.x, l = tid & 63, w = tid >> 6;
    int row = r0 + l;

    float m = -INFINITY, se = 0.0f;
    for (int nt = w; nt < NT_; nt += 4) {
        float pmv = pm[(size_t)nt * B_N + row];
        float psev = pse[(size_t)nt * B_N + row];
        float nm = fmaxf(m, pmv);
        se = se * __expf(m - nm) + psev * __expf(pmv - nm);
        m = nm;
    }
    sm[w][l] = m; ss[w][l] = se;
    __syncthreads();
    if (tid < 64) {
        float M = fmaxf(fmaxf(sm[0][l], sm[1][l]), fmaxf(sm[2][l], sm[3][l]));
        float S = ss[0][l] * __expf(sm[0][l] - M) + ss[1][l] * __expf(sm[1][l] - M) +
                  ss[2][l] * __expf(sm[2][l] - M) + ss[3][l] * __expf(sm[3][l] - M);
        float lse = M + logf(S);
        float st = tlogit[r0 + l];
        float corr = __expf(st - lse) * (__expf(-SCALE_F * MARGIN_F) - 1.0f);
        float lse2 = lse + log1pf(corr);
        float nll = lse2 - (st - SCALE_F * MARGIN_F);
#pragma unroll
        for (int xm = 1; xm < 64; xm <<= 1) nll += __shfl_xor(nll, xm);
        if (l == 0) atomicAdd(&sums[1], nll);
    }
}

// ------------- kernel F: finalize scalar output -------------
__global__ void finalize_kernel(const float* __restrict__ sums, float* __restrict__ out) {
    float disc = sums[0] * (1.0f / B_N);
    float logp = sums[1] * (1.0f / B_N);
    float p = __expf(-logp);
    float om = 1.0f - p;
    out[0] = 0.4f * disc + om * om * logp;
}

extern "C" void kernel_launch(void* const* d_in, const int* in_sizes, int n_in,
                              void* d_out, int out_size, void* d_ws, size_t ws_size,
                              hipStream_t stream) {
    const float* x = (const float*)d_in[0];
    const int* target = (const int*)d_in[1];
    const float* ida = (const float*)d_in[2];
    const float* bmat = (const float*)d_in[3];
    float* out = (float*)d_out;

    char* ws = (char*)d_ws;
    size_t off = 0;
    ushort* xnb = (ushort*)(ws + off);   off += (size_t)B_N * D_K * 2;   // 1 MB
    ushort* wbf = (ushort*)(ws + off);   off += (size_t)C_N * D_K * 2;   // 102.4 MB
    float* pm = (float*)(ws + off);      off += (size_t)NT_ * B_N * 4;   // 3.2 MB
    float* pse = (float*)(ws + off);     off += (size_t)NT_ * B_N * 4;   // 3.2 MB
    float* tlogit = (float*)(ws + off);  off += (size_t)B_N * 4;
    float* sums = (float*)(ws + off);    off += 256;

    hipMemsetAsync(sums, 0, 2 * sizeof(float), stream);

    norm_x_kernel<<<B_N / 4, 256, 0, stream>>>(x, xnb);
    norm_w_kernel<<<C_N / 4, 256, 0, stream>>>(ida, wbf);
    disc_kernel<<<B_N / 4, 256, 0, stream>>>(x, target, ida, bmat, sums, tlogit);
    gemm_lse_kernel<<<MT_ * NT_, 256, 0, stream>>>(xnb, wbf, pm, pse);
    row_lse_kernel<<<B_N / 64, 256, 0, stream>>>(pm, pse, tlogit, sums);
    finalize_kernel<<<1, 1, 0, stream>>>(sums, out);
}

// Round 4
// 190.140 us; speedup vs baseline: 3.2318x; 1.6201x over previous
//
#include <hip/hip_runtime.h>
#include <hip/hip_bf16.h>

typedef __attribute__((ext_vector_type(8))) short short8;
typedef __attribute__((ext_vector_type(4))) float f32x4;

#define B_N 1024
#define D_K 512
#define C_N 100000
#define SCALE_F 64.0f
#define MARGIN_F 0.35f
#define BM 128
#define BN 128
#define BK 64
#define NT_ 782   // ceil(100000/128)
#define MT_ 8     // 1024/128
#define MAXL 64.0f   // global logit bound: |cos|*64 <= 64

__device__ __forceinline__ float dot4(float4 a, float4 b) {
    return a.x * b.x + a.y * b.y + a.z * b.z + a.w * b.w;
}

// round-to-nearest-even f32 -> bf16 bits
__device__ __forceinline__ ushort f2b(float f) {
    unsigned int u = __float_as_uint(f);
    u = (u + 0x7FFFu + ((u >> 16) & 1u)) >> 16;
    return (ushort)u;
}

// ---------------- kernel A: normalize x rows -> bf16 ----------------
__global__ void norm_x_kernel(const float* __restrict__ x,
                              ushort* __restrict__ xnb) {
    int row = blockIdx.x * 4 + (threadIdx.x >> 6);
    int l = threadIdx.x & 63;
    const float4* rp = (const float4*)(x + (size_t)row * D_K);
    float4 a = rp[l], b = rp[64 + l];
    float ssq = dot4(a, a) + dot4(b, b);
#pragma unroll
    for (int m = 1; m < 64; m <<= 1) ssq += __shfl_xor(ssq, m);
    float inv = 1.0f / fmaxf(sqrtf(ssq), 1e-12f);
    a.x *= inv; a.y *= inv; a.z *= inv; a.w *= inv;
    b.x *= inv; b.y *= inv; b.z *= inv; b.w *= inv;
    ushort4 ua; ua.x = f2b(a.x); ua.y = f2b(a.y); ua.z = f2b(a.z); ua.w = f2b(a.w);
    ushort4 ub; ub.x = f2b(b.x); ub.y = f2b(b.y); ub.z = f2b(b.z); ub.w = f2b(b.w);
    ushort4* obp = (ushort4*)(xnb + (size_t)row * D_K);
    obp[l] = ua; obp[64 + l] = ub;
}

// ---------------- kernel B: normalize id_agent rows -> bf16 ----------------
__global__ void norm_w_kernel(const float* __restrict__ w,
                              ushort* __restrict__ wb) {
    int row = blockIdx.x * 4 + (threadIdx.x >> 6);
    int l = threadIdx.x & 63;
    const float4* rp = (const float4*)(w + (size_t)row * D_K);
    float4 a = rp[l], b = rp[64 + l];
    float ssq = dot4(a, a) + dot4(b, b);
#pragma unroll
    for (int m = 1; m < 64; m <<= 1) ssq += __shfl_xor(ssq, m);
    float inv = 1.0f / fmaxf(sqrtf(ssq), 1e-12f);
    a.x *= inv; a.y *= inv; a.z *= inv; a.w *= inv;
    b.x *= inv; b.y *= inv; b.z *= inv; b.w *= inv;
    ushort4 ua; ua.x = f2b(a.x); ua.y = f2b(a.y); ua.z = f2b(a.z); ua.w = f2b(a.w);
    ushort4 ub; ub.x = f2b(b.x); ub.y = f2b(b.y); ub.z = f2b(b.z); ub.w = f2b(b.w);
    ushort4* obp = (ushort4*)(wb + (size_t)row * D_K);
    obp[l] = ua; obp[64 + l] = ub;
}

// ------------- kernel C: disc loss partial + exact target logit -------------
__global__ void disc_kernel(const float* __restrict__ x,
                            const int* __restrict__ target,
                            const float* __restrict__ ida,
                            const float* __restrict__ bmat,
                            float* __restrict__ sums,
                            float* __restrict__ tlogit) {
    int row = blockIdx.x * 4 + (threadIdx.x >> 6);
    int l = threadIdx.x & 63;
    long t = (long)target[row];
    const float4* xp = (const float4*)(x + (size_t)row * D_K);
    const float4* wp = (const float4*)(ida + (size_t)t * D_K);
    const float4* bp = (const float4*)(bmat + (size_t)t * D_K);
    float4 x0 = xp[l], x1 = xp[64 + l];
    float4 w0 = wp[l], w1 = wp[64 + l];
    float4 b0 = bp[l], b1 = bp[64 + l];
    float xssq = dot4(x0, x0) + dot4(x1, x1);
    float wssq = dot4(w0, w0) + dot4(w1, w1);
    float bssq = dot4(b0, b0) + dot4(b1, b1);
#pragma unroll
    for (int m = 1; m < 64; m <<= 1) {
        xssq += __shfl_xor(xssq, m);
        wssq += __shfl_xor(wssq, m);
        bssq += __shfl_xor(bssq, m);
    }
    float xinv = 1.0f / fmaxf(sqrtf(xssq), 1e-12f);
    float winv = 1.0f / fmaxf(sqrtf(wssq), 1e-12f);
    float btn = sqrtf(bssq);
    float cs = fminf(btn, 0.05f) / fmaxf(btn, 1e-12f);

    float xs[8] = {x0.x, x0.y, x0.z, x0.w, x1.x, x1.y, x1.z, x1.w};
    float wv[8] = {w0.x, w0.y, w0.z, w0.w, w1.x, w1.y, w1.z, w1.w};
    float bv[8] = {b0.x, b0.y, b0.z, b0.w, b1.x, b1.y, b1.z, b1.w};
    float rss = 0.0f, dt = 0.0f;
#pragma unroll
    for (int i = 0; i < 8; ++i) {
        float xn = xs[i] * xinv;
        float wn = wv[i] * winv;
        float d = xn - wn;
        float r = d - bv[i] * cs;
        rss += r * r;
        dt += xn * wn;
    }
#pragma unroll
    for (int m = 1; m < 64; m <<= 1) {
        rss += __shfl_xor(rss, m);
        dt += __shfl_xor(dt, m);
    }
    if (l == 0) {
        atomicAdd(&sums[0], sqrtf(rss));
        tlogit[row] = SCALE_F * dt;
    }
}

// ------------- kernel D: bf16 MFMA GEMM, XCD-swizzled, XOR-swizzled LDS,
//               fixed-max sumexp epilogue with per-row atomic accumulate -------------
__global__ __launch_bounds__(256, 4) void gemm_lse_kernel(const ushort* __restrict__ A,
                                                          const ushort* __restrict__ W,
                                                          float* __restrict__ rowsum) {
    __shared__ ushort As[BM * BK];   // 16 KB, [row][8 slots of 16B], slots XOR-permuted
    __shared__ ushort Bs[BN * BK];   // 16 KB
    __shared__ float rs[2][BM];

    int tid = threadIdx.x;
    int wave = tid >> 6, l = tid & 63;
    int wm = wave >> 1, wn = wave & 1;

    // XCD-bijective swizzle: xcd = bid % 8 gets a contiguous chunk of tile-space
    // ordered (nt major, mt minor) so 8 blocks sharing a W-tile share one L2.
    int tile = (blockIdx.x & 7) * NT_ + (blockIdx.x >> 3);
    int nt = tile >> 3, mt = tile & 7;
    int m0 = mt * BM, n0 = nt * BN;

    int srow = l >> 3;                      // row 0..7 within an 8-row staging chunk
    int scol = ((l & 7) ^ (l >> 3)) * 8;    // pre-swizzled global slot (rule #21)

    f32x4 zero4 = {0.0f, 0.0f, 0.0f, 0.0f};
    f32x4 acc[4][4];
#pragma unroll
    for (int i = 0; i < 4; ++i)
#pragma unroll
        for (int j = 0; j < 4; ++j) acc[i][j] = zero4;

    int cl = l & 15, hi = l >> 4;

    for (int kt = 0; kt < D_K; kt += BK) {
#pragma unroll
        for (int i = 0; i < 4; ++i) {
            int rb = wave * 32 + i * 8;
            const ushort* ga = A + (size_t)(m0 + rb + srow) * D_K + kt + scol;
            __builtin_amdgcn_global_load_lds(
                (const __attribute__((address_space(1))) void*)ga,
                (__attribute__((address_space(3))) void*)&As[rb * BK], 16, 0, 0);
            int rn = n0 + rb + srow;
            rn = rn < C_N ? rn : C_N - 1;
            const ushort* gb = W + (size_t)rn * D_K + kt + scol;
            __builtin_amdgcn_global_load_lds(
                (const __attribute__((address_space(1))) void*)gb,
                (__attribute__((address_space(3))) void*)&Bs[rb * BK], 16, 0, 0);
        }
        __syncthreads();

#pragma unroll
        for (int kk = 0; kk < 2; ++kk) {
            // physical slot = logical slot (kk*4+hi) XOR (row&7); row&7 == cl&7
            int px = (((kk << 2) | hi) ^ (cl & 7)) * 8;
            short8 af[4], bfr[4];
#pragma unroll
            for (int mi = 0; mi < 4; ++mi)
                af[mi] = *(const short8*)&As[(wm * 64 + mi * 16 + cl) * BK + px];
#pragma unroll
            for (int ni = 0; ni < 4; ++ni)
                bfr[ni] = *(const short8*)&Bs[(wn * 64 + ni * 16 + cl) * BK + px];
#pragma unroll
            for (int mi = 0; mi < 4; ++mi)
#pragma unroll
                for (int ni = 0; ni < 4; ++ni)
                    acc[mi][ni] = __builtin_amdgcn_mfma_f32_16x16x32_bf16(af[mi], bfr[ni], acc[mi][ni], 0, 0, 0);
        }
        __syncthreads();
    }

    // epilogue: per-row sum of exp(s - 64); logits are cosines*64 so s <= 64 always
#pragma unroll
    for (int mi = 0; mi < 4; ++mi) {
#pragma unroll
        for (int j = 0; j < 4; ++j) {
            float se = 0.0f;
#pragma unroll
            for (int ni = 0; ni < 4; ++ni) {
                int cg = n0 + wn * 64 + ni * 16 + cl;
                if (cg < C_N) se += __expf(acc[mi][ni][j] * SCALE_F - MAXL);
            }
#pragma unroll
            for (int xm = 1; xm < 16; xm <<= 1) se += __shfl_xor(se, xm);
            if (cl == 0) rs[wn][wm * 64 + mi * 16 + hi * 4 + j] = se;
        }
    }
    __syncthreads();
    if (tid < BM) {
        float s = rs[0][tid] + rs[1][tid];
        atomicAdd(&rowsum[m0 + tid], s);
    }
}

// ------------- kernel E: per-row lse from fixed-max sumexp -> nll -> sums[1] -------------
__global__ void rowfin_kernel(const float* __restrict__ rowsum,
                              const float* __restrict__ tlogit,
                              float* __restrict__ sums) {
    __shared__ float red[4];
    int tid = threadIdx.x;
    int row = blockIdx.x * 256 + tid;
    float lse = MAXL + logf(rowsum[row]);
    float st = tlogit[row];
    // replace exp(st) by exp(st - 64*margin) inside the lse
    float corr = __expf(st - lse) * (__expf(-SCALE_F * MARGIN_F) - 1.0f);
    float lse2 = lse + log1pf(corr);
    float nll = lse2 - (st - SCALE_F * MARGIN_F);
#pragma unroll
    for (int xm = 1; xm < 64; xm <<= 1) nll += __shfl_xor(nll, xm);
    if ((tid & 63) == 0) red[tid >> 6] = nll;
    __syncthreads();
    if (tid == 0) atomicAdd(&sums[1], red[0] + red[1] + red[2] + red[3]);
}

// ------------- kernel F: finalize scalar output -------------
__global__ void finalize_kernel(const float* __restrict__ sums, float* __restrict__ out) {
    float disc = sums[0] * (1.0f / B_N);
    float logp = sums[1] * (1.0f / B_N);
    float p = __expf(-logp);
    float om = 1.0f - p;
    out[0] = 0.4f * disc + om * om * logp;
}

extern "C" void kernel_launch(void* const* d_in, const int* in_sizes, int n_in,
                              void* d_out, int out_size, void* d_ws, size_t ws_size,
                              hipStream_t stream) {
    const float* x = (const float*)d_in[0];
    const int* target = (const int*)d_in[1];
    const float* ida = (const float*)d_in[2];
    const float* bmat = (const float*)d_in[3];
    float* out = (float*)d_out;

    char* ws = (char*)d_ws;
    size_t off = 0;
    float* rowsum = (float*)(ws + off);  off += (size_t)B_N * 4;         // 4 KB
    float* sums = (float*)(ws + off);    off += 256;
    ushort* xnb = (ushort*)(ws + off);   off += (size_t)B_N * D_K * 2;   // 1 MB
    ushort* wbf = (ushort*)(ws + off);   off += (size_t)C_N * D_K * 2;   // 102.4 MB
    float* tlogit = (float*)(ws + off);  off += (size_t)B_N * 4;

    // zero rowsum + sums (contiguous region) every call — deterministic
    hipMemsetAsync(rowsum, 0, (size_t)B_N * 4 + 256, stream);

    norm_x_kernel<<<B_N / 4, 256, 0, stream>>>(x, xnb);
    norm_w_kernel<<<C_N / 4, 256, 0, stream>>>(ida, wbf);
    disc_kernel<<<B_N / 4, 256, 0, stream>>>(x, target, ida, bmat, sums, tlogit);
    gemm_lse_kernel<<<MT_ * NT_, 256, 0, stream>>>(xnb, wbf, rowsum);
    rowfin_kernel<<<B_N / 256, 256, 0, stream>>>(rowsum, tlogit, sums);
    finalize_kernel<<<1, 1, 0, stream>>>(sums, out);
}